// Round 19
// baseline (146.361 us; speedup 1.0000x reference)
//
#include <hip/hip_runtime.h>
#include <cmath>

// CTC alignment loss (RAD-TTS style), B=64, T<=2000, K<=400, S=2K+1<=801.
//
// Round-18: scan cadence is per-wave (solo ~4.3 cy/instr regardless of
// co-residency), so only shortening each wave's stream helps.
//   * 8-wave scan (512 thr), 2 states/lane: step = 4 VALU + 1 ushort load;
//     halo 24 states -> exchange every 12 steps (single-barrier, dbuf).
//   * prep: lanes with c0 >= L skip loads entirely (~25% less read traffic).

#define T_MAXN 2000
#define K_MAXN 400

typedef uint32_t uint4v __attribute__((ext_vector_type(4)));
typedef float    float2v __attribute__((ext_vector_type(2)));

// ws layout (fast path)
#define G_BYTES   ((size_t)64 * T_MAXN * K_MAXN * 2)   // 102,400,000
#define LSE_OFF   G_BYTES
#define LSE_BYTES ((size_t)64 * T_MAXN * 4)            // 512,000
#define ZERO_OFF  (LSE_OFF + LSE_BYTES)                // 4KB zero block
#define LOSS_OFF  (ZERO_OFF + 4096)
#define WS_NEED   (LOSS_OFF + 64 * 4)

// lane-1's value (shift wave right by 1), lane 0 -> 0.0f; single VALU op
__device__ __forceinline__ float dpp_wave_shr1(float x)
{
    int r = __builtin_amdgcn_update_dpp(0, (int)__float_as_uint(x),
                                        0x138 /*wave_shr:1*/, 0xF, 0xF, true);
    return __uint_as_float((uint32_t)r);
}

template <int CTRL>
__device__ __forceinline__ float dpp_mov(float x)
{
    int r = __builtin_amdgcn_update_dpp(0, (int)__float_as_uint(x),
                                        CTRL, 0xF, 0xF, true);
    return __uint_as_float((uint32_t)r);
}

// ---------------------------------------------------------- fast path: prep
__global__ __launch_bounds__(256)
void prep_kernel(const float* __restrict__ ap_all,
                 const int* __restrict__ in_lens,
                 const int* __restrict__ out_lens,
                 float* __restrict__ lse_out,
                 _Float16* __restrict__ g_out,
                 float* __restrict__ zerobuf)
{
    const int b    = blockIdx.y;
    const int L    = in_lens[b];
    const int Tn   = out_lens[b];
    const int lane = threadIdx.x & 63;
    const int wid  = blockIdx.x * (blockDim.x >> 6) + (threadIdx.x >> 6);
    const int nw   = gridDim.x * (blockDim.x >> 6);

    if (b == 0 && wid == 0) {                     // 4KB zero block for dead lanes
        for (int i = lane; i < 1024; i += 64) zerobuf[i] = 0.0f;
    }

    const float* base = ap_all + (size_t)b * (T_MAXN * K_MAXN);
    _Float16*    gb   = g_out  + (size_t)b * (T_MAXN * K_MAXN);
    const int c0 = lane * 8;
    const int cb = (c0 < 392) ? c0 : 392;         // float4-safe base
    const bool ldon = (c0 < L);                   // fully-masked lanes skip loads

    for (int t = wid; t < Tn; t += nw) {
        float v[8];
        if (ldon) {
            const float4* p = reinterpret_cast<const float4*>(base + (size_t)t * K_MAXN + cb);
            float4 x0 = p[0], x1 = p[1];
            v[0]=x0.x; v[1]=x0.y; v[2]=x0.z; v[3]=x0.w;
            v[4]=x1.x; v[5]=x1.y; v[6]=x1.z; v[7]=x1.w;
        } else {
            #pragma unroll
            for (int j = 0; j < 8; ++j) v[j] = -1e30f;
        }
        float m = -1.0f;                          // blank logit
        #pragma unroll
        for (int j = 0; j < 8; ++j) {
            v[j] = (c0 + j < L) ? v[j] : -1e30f;
            m = fmaxf(m, v[j]);
        }
        #pragma unroll
        for (int off = 32; off; off >>= 1) m = fmaxf(m, __shfl_xor(m, off));
        float s = (lane == 0) ? __expf(-1.0f - m) : 0.0f;
        #pragma unroll
        for (int j = 0; j < 8; ++j) s += __expf(v[j] - m);
        #pragma unroll
        for (int off = 32; off; off >>= 1) s += __shfl_xor(s, off);
        if (lane == 0) lse_out[b * T_MAXN + t] = m + __logf(s);

        _Float16 h[8];
        #pragma unroll
        for (int j = 0; j < 8; ++j) h[j] = (_Float16)__expf(v[j] + 1.0f);  // masked -> 0
        if (c0 < K_MAXN)
            *reinterpret_cast<uint4v*>(gb + (size_t)t * K_MAXN + c0) =
                *reinterpret_cast<const uint4v*>(h);
    }
}

// ---------------------------------------------------------- fast path: scan
// 8 waves/block, 1 block/sample. Wave w: extended states [104w-24, 104w+104),
// 2 states/lane (even s0=104w-24+2*lane, odd s0+1). Odd-state label col =
// 52w-12+lane -> ONE ushort of g per row per lane.
__global__ __launch_bounds__(512, 1)
void ctc_scan8w_kernel(const char* wsro,
                       const int* __restrict__ in_lens,
                       const int* __restrict__ out_lens,
                       float* loss_out)
{
    __shared__ float afin[1024];
    __shared__ float halo_sh[2][8][24];   // double-buffered (parity)
    __shared__ float wmax_sh[2][8];

    const int b    = blockIdx.x;
    const int tid  = threadIdx.x;
    const int wid  = tid >> 6;
    const int lane = tid & 63;
    const int L    = in_lens[b];      // [200,400]
    const int Tn   = out_lens[b];     // [1000,2000]
    const uint32_t goff = (uint32_t)b * (uint32_t)(T_MAXN * K_MAXN * 2);
    const float* lse = (const float*)(wsro + LSE_OFF) + b * T_MAXN;

    const int col0 = 52 * wid - 12 + lane;    // this lane's single label col
    uint32_t off, inc;
    if (col0 >= 0 && col0 < K_MAXN) { off = goff + (uint32_t)(col0 * 2) + 800u; inc = 800u; }
    else                            { off = (uint32_t)ZERO_OFF;                 inc = 0u;   }

    // prologue: sl = sum_{t<Tn} lse[t]   (wave 0 only; used by tid 0)
    float sl = 0.0f;
    if (wid == 0) {
        for (int t = lane; t < Tn; t += 64) sl += lse[t];
        #pragma unroll
        for (int o = 32; o; o >>= 1) sl += __shfl_xor(sl, o);
    }

    // init t=0 (blank-normalized): state0 -> wave0 lane12 a0=1; state1 -> a1=g[0][0]
    float a0 = 0.0f, a1 = 0.0f;
    if (wid == 0 && lane == 12) {
        a0 = 1.0f;
        a1 = (float)*reinterpret_cast<const _Float16*>(wsro + goff);
    }
    int   E  = 0;
    float t1 = dpp_wave_shr1(a1);   // left neighbor's odd state at t=0 (state 1 for lane 13!)

    #define LOAD1(Q) do { \
        Q = (uint32_t)*reinterpret_cast<const uint16_t*>(wsro + off); \
        off += inc; \
    } while (0)

    // f16 factor consumed directly: a1 = f16*o + 0 (exact convert+mul)
    #define FMIXLO(DST, SRC, O) \
        asm("v_fma_mix_f32 %0, %1, %2, 0 op_sel:[0,0,0] op_sel_hi:[1,0,0]" \
            : "=v"(DST) : "v"(SRC), "v"(O))

    // even: e = a0 + t1; odd: o = a1 + e; a1 = g*o — 4 VALU
    #define STEPF(Q) do { \
        const float e = a0 + t1; \
        const float o = a1 + e; \
        a0 = e; \
        FMIXLO(a1, (Q), o); \
        t1 = dpp_wave_shr1(a1); \
    } while (0)

    // single raw barrier: LDS-visibility only (lgkmcnt), prefetch NOT drained
    #define BARR do { \
        asm volatile("s_waitcnt lgkmcnt(0)" ::: "memory"); \
        __builtin_amdgcn_s_barrier(); \
        asm volatile("" ::: "memory"); \
    } while (0)

    // every 12 steps: boundary handoff + block-max pow2 rescale. Wave w lanes
    // 52..63 (owned top 24 states = next wave's halo) -> LDS buf [pp]; wave
    // w>0 lanes 0..11 reload; all scale by 2^-e of block max. SINGLE barrier
    // (next exchange writes buf [pp^1]; WAR distance = 12 steps).
    #define EXCHANGE(PP) do { \
        float mx = fmaxf(a0, a1); \
        mx = fmaxf(mx, dpp_mov<0x111>(mx)); \
        mx = fmaxf(mx, dpp_mov<0x112>(mx)); \
        mx = fmaxf(mx, dpp_mov<0x114>(mx)); \
        mx = fmaxf(mx, dpp_mov<0x118>(mx)); \
        mx = fmaxf(mx, dpp_mov<0x142>(mx)); \
        mx = fmaxf(mx, dpp_mov<0x143>(mx)); \
        if (lane == 63) wmax_sh[PP][wid] = mx; \
        if (lane >= 52) { \
            float2v bv; bv.x = a0; bv.y = a1; \
            *reinterpret_cast<float2v*>(&halo_sh[PP][wid][(lane - 52) * 2]) = bv; \
        } \
        BARR; \
        float bm = fmaxf(fmaxf(fmaxf(wmax_sh[PP][0], wmax_sh[PP][1]), \
                               fmaxf(wmax_sh[PP][2], wmax_sh[PP][3])), \
                         fmaxf(fmaxf(wmax_sh[PP][4], wmax_sh[PP][5]), \
                               fmaxf(wmax_sh[PP][6], wmax_sh[PP][7]))); \
        int e = (int)((__float_as_uint(bm) >> 23) & 0xFF) - 127; \
        E += e; \
        const float sc = __uint_as_float((uint32_t)(127 - e) << 23);  /* 2^-e exact */ \
        if (wid > 0 && lane < 12) { \
            float2v hv = *reinterpret_cast<const float2v*>(&halo_sh[PP][wid - 1][lane * 2]); \
            a0 = hv.x; a1 = hv.y; \
        } \
        a0 *= sc; a1 *= sc; \
        t1 = dpp_wave_shr1(a1); \
    } while (0)

    uint32_t q0,q1,q2,q3,q4,q5,q6,q7,q8,q9,q10,q11;
    LOAD1(q0); LOAD1(q1); LOAD1(q2);  LOAD1(q3);
    LOAD1(q4); LOAD1(q5); LOAD1(q6);  LOAD1(q7);
    LOAD1(q8); LOAD1(q9); LOAD1(q10); LOAD1(q11);

    int t = 1;
    int pp = 0;
    while (t + 11 < Tn) {
        STEPF(q0);  LOAD1(q0);
        STEPF(q1);  LOAD1(q1);
        STEPF(q2);  LOAD1(q2);
        STEPF(q3);  LOAD1(q3);
        STEPF(q4);  LOAD1(q4);
        STEPF(q5);  LOAD1(q5);
        STEPF(q6);  LOAD1(q6);
        STEPF(q7);  LOAD1(q7);
        STEPF(q8);  LOAD1(q8);
        STEPF(q9);  LOAD1(q9);
        STEPF(q10); LOAD1(q10);
        STEPF(q11); LOAD1(q11);
        EXCHANGE(pp);
        pp ^= 1;
        t += 12;
    }
    {
        const int r = Tn - t;   // 0..11; corruption <= 22 <= 24 -> owned ok
        if (r > 0)  STEPF(q0);
        if (r > 1)  STEPF(q1);
        if (r > 2)  STEPF(q2);
        if (r > 3)  STEPF(q3);
        if (r > 4)  STEPF(q4);
        if (r > 5)  STEPF(q5);
        if (r > 6)  STEPF(q6);
        if (r > 7)  STEPF(q7);
        if (r > 8)  STEPF(q8);
        if (r > 9)  STEPF(q9);
        if (r > 10) STEPF(q10);
    }

    // readout: owned lanes (>=12) publish their 2 states
    if (lane >= 12) {
        const int gidx = 104 * wid - 24 + 2 * lane;   // global state index of a0
        afin[gidx]     = a0;
        afin[gidx + 1] = a1;
    }
    __syncthreads();
    if (tid == 0) {
        float tot = afin[2 * L] + afin[2 * L - 1];
        float lossb = 0.0f;
        if (tot > 0.0f) {
            double ll = log((double)tot)
                      + (double)E * 0.69314718055994530942
                      + (double)(-(double)Tn - (double)sl);
            lossb = (float)(-ll / (double)L);
        }
        loss_out[b] = lossb;
    }
    #undef STEPF
    #undef FMIXLO
    #undef LOAD1
    #undef BARR
    #undef EXCHANGE
}

// ------------------------------------------------- fallback (round-3, proven)
__global__ __launch_bounds__(256)
void lse_kernel(const float* __restrict__ ap_all,
                const int* __restrict__ in_lens,
                float* __restrict__ lse_out)
{
    const int lane = threadIdx.x & 63;
    const int wglob = blockIdx.x * (blockDim.x >> 6) + (threadIdx.x >> 6);
    const int nwav = gridDim.x * (blockDim.x >> 6);
    const int nrows = 64 * T_MAXN;

    for (int row = wglob; row < nrows; row += nwav) {
        const int b = row / T_MAXN;
        const int L = in_lens[b];
        const float* rp = ap_all + (size_t)row * K_MAXN;
        const int c0 = lane * 8;
        const int cb = (c0 < 392) ? c0 : 392;
        const float4* p = reinterpret_cast<const float4*>(rp + cb);
        float4 x0 = p[0], x1 = p[1];
        float v[8] = {x0.x, x0.y, x0.z, x0.w, x1.x, x1.y, x1.z, x1.w};
        float m = -1.0f;
        #pragma unroll
        for (int j = 0; j < 8; ++j) {
            v[j] = (c0 + j < L) ? v[j] : -1e30f;
            m = fmaxf(m, v[j]);
        }
        #pragma unroll
        for (int off = 32; off; off >>= 1) m = fmaxf(m, __shfl_xor(m, off));
        float s = (lane == 0) ? __expf(-1.0f - m) : 0.0f;
        #pragma unroll
        for (int j = 0; j < 8; ++j) s += __expf(v[j] - m);
        #pragma unroll
        for (int off = 32; off; off >>= 1) s += __shfl_xor(s, off);
        if (lane == 0) lse_out[row] = m + __logf(s);
    }
}

__global__ __launch_bounds__(64)
void ctc_scan_kernel(const float* __restrict__ ap_all,
                     const int* __restrict__ in_lens,
                     const int* __restrict__ out_lens,
                     const float* __restrict__ lse_all,
                     float* __restrict__ loss_out)
{
    __shared__ float afin[1024];

    const int b    = blockIdx.x;
    const int lane = threadIdx.x;
    const int L    = in_lens[b];
    const int Tn   = out_lens[b];
    const float* ap  = ap_all + (size_t)b * (T_MAXN * K_MAXN);
    const float* lse = lse_all + b * T_MAXN;

    const float LOG2E = 1.4426950408889634f;
    const int c0 = lane * 8;
    const int cb = (c0 < 392) ? c0 : 392;
    const float* rbase = ap + cb;
    float fa0,fa1,fa2,fa3,fa4,fa5,fa6,fa7;
    float fb0,fb1,fb2,fb3,fb4,fb5,fb6,fb7;
    #define MASKC(J, FA, FB) do { bool ok = (c0 + (J)) < L; \
        FA = ok ? LOG2E : 0.0f; FB = ok ? LOG2E : -1000.0f; } while (0)
    MASKC(0,fa0,fb0); MASKC(1,fa1,fb1); MASKC(2,fa2,fb2); MASKC(3,fa3,fb3);
    MASKC(4,fa4,fb4); MASKC(5,fa5,fb5); MASKC(6,fa6,fb6); MASKC(7,fa7,fb7);
    #undef MASKC

    float4 p0a,p0b,p1a,p1b,p2a,p2b,p3a,p3b;
    #define LOADROW(PA, PB, T) do { \
        const float4* _p = reinterpret_cast<const float4*>(rbase + (size_t)(T) * K_MAXN); \
        PA = _p[0]; PB = _p[1]; } while (0)
    LOADROW(p0a,p0b,1); LOADROW(p1a,p1b,2); LOADROW(p2a,p2b,3); LOADROW(p3a,p3b,4);

    float sl = 0.0f;
    for (int t = lane; t < Tn; t += 64) sl += lse[t];
    #pragma unroll
    for (int off = 32; off; off >>= 1) sl += __shfl_xor(sl, off);

    float x00 = ap[0];
    float a0=0,a1=0,a2=0,a3=0,a4=0,a5=0,a6=0,a7=0;
    float a8=0,a9=0,a10=0,a11=0,a12=0,a13=0,a14=0,a15=0;
    if (lane == 0) {
        a0 = 1.0f;
        a1 = __builtin_amdgcn_exp2f(fmaf(x00, LOG2E, LOG2E));
    }
    int E = 0;

    #define STEP(A0, A1) do { \
        float t1 = __shfl_up(a15, 1); \
        t1 = lane ? t1 : 0.0f; \
        const float f0 = __builtin_amdgcn_exp2f(fmaf((A0).x, fa0, fb0)); \
        const float f1 = __builtin_amdgcn_exp2f(fmaf((A0).y, fa1, fb1)); \
        const float f2 = __builtin_amdgcn_exp2f(fmaf((A0).z, fa2, fb2)); \
        const float f3 = __builtin_amdgcn_exp2f(fmaf((A0).w, fa3, fb3)); \
        const float f4 = __builtin_amdgcn_exp2f(fmaf((A1).x, fa4, fb4)); \
        const float f5 = __builtin_amdgcn_exp2f(fmaf((A1).y, fa5, fb5)); \
        const float f6 = __builtin_amdgcn_exp2f(fmaf((A1).z, fa6, fb6)); \
        const float f7 = __builtin_amdgcn_exp2f(fmaf((A1).w, fa7, fb7)); \
        const float e0 = a0 + t1,   e1 = a2 + a1,   e2 = a4 + a3,   e3 = a6 + a5; \
        const float e4 = a8 + a7,   e5 = a10 + a9,  e6 = a12 + a11, e7 = a14 + a13; \
        const float o0 = a1 + e0,   o1 = a3 + e1,   o2 = a5 + e2,   o3 = a7 + e3; \
        const float o4 = a9 + e4,   o5 = a11 + e5,  o6 = a13 + e6,  o7 = a15 + e7; \
        a0 = e0; a2 = e1; a4 = e2; a6 = e3; a8 = e4; a10 = e5; a12 = e6; a14 = e7; \
        a1 = f0*o0; a3 = f1*o1; a5 = f2*o2; a7 = f3*o3; \
        a9 = f4*o4; a11 = f5*o5; a13 = f6*o6; a15 = f7*o7; \
    } while (0)

    #define RESCALE do { \
        float mx = fmaxf(fmaxf(fmaxf(fmaxf(a0,a1),fmaxf(a2,a3)),fmaxf(fmaxf(a4,a5),fmaxf(a6,a7))), \
                         fmaxf(fmaxf(fmaxf(a8,a9),fmaxf(a10,a11)),fmaxf(fmaxf(a12,a13),fmaxf(a14,a15)))); \
        _Pragma("unroll") \
        for (int off = 32; off; off >>= 1) mx = fmaxf(mx, __shfl_xor(mx, off)); \
        int e = (int)((__float_as_uint(mx) >> 23) & 0xFF) - 127; \
        if (e != 0) { \
            E += e; \
            a0 = ldexpf(a0,-e);  a1 = ldexpf(a1,-e);  a2 = ldexpf(a2,-e);  a3 = ldexpf(a3,-e); \
            a4 = ldexpf(a4,-e);  a5 = ldexpf(a5,-e);  a6 = ldexpf(a6,-e);  a7 = ldexpf(a7,-e); \
            a8 = ldexpf(a8,-e);  a9 = ldexpf(a9,-e);  a10= ldexpf(a10,-e); a11= ldexpf(a11,-e); \
            a12= ldexpf(a12,-e); a13= ldexpf(a13,-e); a14= ldexpf(a14,-e); a15= ldexpf(a15,-e); \
        } \
    } while (0)

    int t = 1;
    while (t + 3 < Tn) {
        int tl;
        STEP(p0a,p0b); tl = (t+4 < T_MAXN) ? t+4 : T_MAXN-1; LOADROW(p0a,p0b,tl);
        STEP(p1a,p1b); tl = (t+5 < T_MAXN) ? t+5 : T_MAXN-1; LOADROW(p1a,p1b,tl);
        STEP(p2a,p2b); tl = (t+6 < T_MAXN) ? t+6 : T_MAXN-1; LOADROW(p2a,p2b,tl);
        STEP(p3a,p3b); tl = (t+7 < T_MAXN) ? t+7 : T_MAXN-1; LOADROW(p3a,p3b,tl);
        if ((t & 7) == 5) RESCALE;
        t += 4;
    }
    if (t < Tn) { STEP(p0a,p0b); ++t; }
    if (t < Tn) { STEP(p1a,p1b); ++t; }
    if (t < Tn) { STEP(p2a,p2b); ++t; }

    afin[16*lane+0]=a0;  afin[16*lane+1]=a1;  afin[16*lane+2]=a2;  afin[16*lane+3]=a3;
    afin[16*lane+4]=a4;  afin[16*lane+5]=a5;  afin[16*lane+6]=a6;  afin[16*lane+7]=a7;
    afin[16*lane+8]=a8;  afin[16*lane+9]=a9;  afin[16*lane+10]=a10; afin[16*lane+11]=a11;
    afin[16*lane+12]=a12; afin[16*lane+13]=a13; afin[16*lane+14]=a14; afin[16*lane+15]=a15;
    __syncthreads();
    if (lane == 0) {
        float tot = afin[2*L] + afin[2*L-1];
        float lossb = 0.0f;
        if (tot > 0.0f) {
            double ll = log((double)tot)
                      + (double)E * 0.69314718055994530942
                      + (double)(-(double)Tn - (double)sl);
            lossb = (float)(-ll / (double)L);
        }
        loss_out[b] = lossb;
    }
    #undef STEP
    #undef RESCALE
    #undef LOADROW
}

// ---------------------------------------------------------------- mean
__global__ void mean_kernel(const float* __restrict__ loss, float* __restrict__ out)
{
    float v = loss[threadIdx.x];   // 64 threads
    #pragma unroll
    for (int off = 32; off; off >>= 1) v += __shfl_xor(v, off);
    if (threadIdx.x == 0) out[0] = v * (1.0f / 64.0f);
}

extern "C" void kernel_launch(void* const* d_in, const int* in_sizes, int n_in,
                              void* d_out, int out_size, void* d_ws, size_t ws_size,
                              hipStream_t stream)
{
    // setup_inputs order: attn (unused), in_lens, out_lens, attn_logprob
    const int*   in_lens  = (const int*)d_in[1];
    const int*   out_lens = (const int*)d_in[2];
    const float* ap       = (const float*)d_in[3];
    float*       out      = (float*)d_out;

    if (ws_size >= WS_NEED) {
        char*     wsb     = (char*)d_ws;
        _Float16* g       = (_Float16*)wsb;
        float*    lse_ws  = (float*)(wsb + LSE_OFF);
        float*    zb      = (float*)(wsb + ZERO_OFF);
        float*    loss_ws = (float*)(wsb + LOSS_OFF);
        hipLaunchKernelGGL(prep_kernel, dim3(32, 64), dim3(256), 0, stream,
                           ap, in_lens, out_lens, lse_ws, g, zb);
        hipLaunchKernelGGL(ctc_scan8w_kernel, dim3(64), dim3(512), 0, stream,
                           (const char*)wsb, in_lens, out_lens, loss_ws);
        hipLaunchKernelGGL(mean_kernel, dim3(1), dim3(64), 0, stream, loss_ws, out);
    } else {
        float* lse_ws  = (float*)d_ws;
        float* loss_ws = (float*)((char*)d_ws + (size_t)64 * T_MAXN * 4);
        hipLaunchKernelGGL(lse_kernel, dim3(512), dim3(256), 0, stream,
                           ap, in_lens, lse_ws);
        hipLaunchKernelGGL(ctc_scan_kernel, dim3(64), dim3(64), 0, stream,
                           ap, in_lens, out_lens, lse_ws, loss_ws);
        hipLaunchKernelGGL(mean_kernel, dim3(1), dim3(64), 0, stream, loss_ws, out);
    }
}

// Round 20
// 117.404 us; speedup vs baseline: 1.2466x; 1.2466x over previous
//
#include <hip/hip_runtime.h>
#include <cmath>

// CTC alignment loss (RAD-TTS style), B=64, T<=2000, K<=400, S=2K+1<=801.
//
// Round-19 post-mortem: 8-wave split regressed (146us vs 117us) — exchange
// frequency x 8-wave barrier rendezvous cost outweighed the ALU savings.
// Round-20: clean revert to the round-17 configuration (verified 116.7us):
// 4-wave halo scan, 16-step interval, single-barrier double-buffered
// exchange, plain compiler-scheduled loads, fma_mix f16 consumption.

#define T_MAXN 2000
#define K_MAXN 400

typedef uint32_t uint4v __attribute__((ext_vector_type(4)));

// ws layout (fast path)
#define G_BYTES   ((size_t)64 * T_MAXN * K_MAXN * 2)   // 102,400,000
#define LSE_OFF   G_BYTES
#define LSE_BYTES ((size_t)64 * T_MAXN * 4)            // 512,000
#define ZERO_OFF  (LSE_OFF + LSE_BYTES)                // 4KB zero block
#define LOSS_OFF  (ZERO_OFF + 4096)
#define WS_NEED   (LOSS_OFF + 64 * 4)

// lane-1's value (shift wave right by 1), lane 0 -> 0.0f; single VALU op
__device__ __forceinline__ float dpp_wave_shr1(float x)
{
    int r = __builtin_amdgcn_update_dpp(0, (int)__float_as_uint(x),
                                        0x138 /*wave_shr:1*/, 0xF, 0xF, true);
    return __uint_as_float((uint32_t)r);
}

template <int CTRL>
__device__ __forceinline__ float dpp_mov(float x)
{
    int r = __builtin_amdgcn_update_dpp(0, (int)__float_as_uint(x),
                                        CTRL, 0xF, 0xF, true);
    return __uint_as_float((uint32_t)r);
}

// ---------------------------------------------------------- fast path: prep
__global__ __launch_bounds__(256)
void prep_kernel(const float* __restrict__ ap_all,
                 const int* __restrict__ in_lens,
                 const int* __restrict__ out_lens,
                 float* __restrict__ lse_out,
                 _Float16* __restrict__ g_out,
                 float* __restrict__ zerobuf)
{
    const int b    = blockIdx.y;
    const int L    = in_lens[b];
    const int Tn   = out_lens[b];
    const int lane = threadIdx.x & 63;
    const int wid  = blockIdx.x * (blockDim.x >> 6) + (threadIdx.x >> 6);
    const int nw   = gridDim.x * (blockDim.x >> 6);

    if (b == 0 && wid == 0) {                     // 4KB zero block for dead lanes
        for (int i = lane; i < 1024; i += 64) zerobuf[i] = 0.0f;
    }

    const float* base = ap_all + (size_t)b * (T_MAXN * K_MAXN);
    _Float16*    gb   = g_out  + (size_t)b * (T_MAXN * K_MAXN);
    const int c0 = lane * 8;
    const int cb = (c0 < 392) ? c0 : 392;         // clamped (lanes >= 50 fully masked)

    for (int t = wid; t < Tn; t += nw) {
        const float4* p = reinterpret_cast<const float4*>(base + (size_t)t * K_MAXN + cb);
        float4 x0 = p[0], x1 = p[1];
        float v[8] = {x0.x, x0.y, x0.z, x0.w, x1.x, x1.y, x1.z, x1.w};
        float m = -1.0f;                          // blank logit
        #pragma unroll
        for (int j = 0; j < 8; ++j) {
            v[j] = (c0 + j < L) ? v[j] : -1e30f;
            m = fmaxf(m, v[j]);
        }
        #pragma unroll
        for (int off = 32; off; off >>= 1) m = fmaxf(m, __shfl_xor(m, off));
        float s = (lane == 0) ? __expf(-1.0f - m) : 0.0f;
        #pragma unroll
        for (int j = 0; j < 8; ++j) s += __expf(v[j] - m);
        #pragma unroll
        for (int off = 32; off; off >>= 1) s += __shfl_xor(s, off);
        if (lane == 0) lse_out[b * T_MAXN + t] = m + __logf(s);

        _Float16 h[8];
        #pragma unroll
        for (int j = 0; j < 8; ++j) h[j] = (_Float16)__expf(v[j] + 1.0f);  // masked -> 0
        if (c0 < K_MAXN)
            *reinterpret_cast<uint4v*>(gb + (size_t)t * K_MAXN + c0) =
                *reinterpret_cast<const uint4v*>(h);
    }
}

// ---------------------------------------------------------- fast path: scan
// 4 waves/block, 1 block/sample. Wave w: extended states [224w-32, 224w+224),
// 4 states/lane (even,odd,even,odd). Odd-state labels -> g columns
// col0 = 112w-16+2*lane and col0+1 (one dword per row per lane).
__global__ __launch_bounds__(256, 1)
void ctc_scan4w_kernel(const char* wsro,
                       const int* __restrict__ in_lens,
                       const int* __restrict__ out_lens,
                       float* loss_out)
{
    __shared__ float afin[1024];
    __shared__ float halo_sh[2][4][32];   // double-buffered (parity)
    __shared__ float wmax_sh[2][4];

    const int b    = blockIdx.x;
    const int tid  = threadIdx.x;
    const int wid  = tid >> 6;
    const int lane = tid & 63;
    const int L    = in_lens[b];      // [200,400]
    const int Tn   = out_lens[b];     // [1000,2000]
    const uint32_t goff = (uint32_t)b * (uint32_t)(T_MAXN * K_MAXN * 2);
    const float* lse = (const float*)(wsro + LSE_OFF) + b * T_MAXN;

    const int col0 = 112 * wid - 16 + 2 * lane;   // even; this lane's 2 label cols
    uint32_t off, inc;
    if (col0 >= 0 && col0 < K_MAXN) { off = goff + (uint32_t)(col0 * 2) + 800u; inc = 3200u; }
    else                            { off = (uint32_t)ZERO_OFF;                 inc = 0u;    }

    // prologue: sl = sum_{t<Tn} lse[t]   (wave 0 only; used by tid 0)
    float sl = 0.0f;
    if (wid == 0) {
        for (int t = lane; t < Tn; t += 64) sl += lse[t];
        #pragma unroll
        for (int o = 32; o; o >>= 1) sl += __shfl_xor(sl, o);
    }

    // init t=0 (blank-normalized): alpha^[0]=1 (wave0 lane8 a0), alpha^[1]=g[0][0]
    float a0=0.0f, a1=0.0f, a2=0.0f, a3=0.0f;
    if (wid == 0 && lane == 8) {
        a0 = 1.0f;
        a1 = (float)*reinterpret_cast<const _Float16*>(wsro + goff);
    }
    int   E  = 0;
    float t1 = 0.0f;    // lane-1's a3 (state E+4l-1); 0 initially (those states are 0)

    // plain loads: compiler schedules + auto-inserts waitcnt (depth immaterial,
    // proven round-12)
    #define LOADG4(QA, QB, QC, QD) do { \
        QA = *reinterpret_cast<const uint32_t*>(wsro + off); \
        QB = *reinterpret_cast<const uint32_t*>(wsro + off + 800); \
        QC = *reinterpret_cast<const uint32_t*>(wsro + off + 1600); \
        QD = *reinterpret_cast<const uint32_t*>(wsro + off + 2400); \
        off += inc; \
    } while (0)

    // f16 factor consumed directly: a = f16*o + 0 (exact convert+mul)
    #define FMIXLO(DST, SRC, O) \
        asm("v_fma_mix_f32 %0, %1, %2, 0 op_sel:[0,0,0] op_sel_hi:[1,0,0]" \
            : "=v"(DST) : "v"(SRC), "v"(O))
    #define FMIXHI(DST, SRC, O) \
        asm("v_fma_mix_f32 %0, %1, %2, 0 op_sel:[1,0,0] op_sel_hi:[1,0,0]" \
            : "=v"(DST) : "v"(SRC), "v"(O))

    // even s: new = old[s]+old[s-1]; odd s: new = g*(old[s]+new_even) — 7 VALU
    #define STEPF(Q) do { \
        const float e0 = a0 + t1; \
        const float e1 = a2 + a1; \
        const float o0 = a1 + e0; \
        const float o1 = a3 + e1; \
        a0 = e0; a2 = e1; \
        FMIXLO(a1, (Q), o0); \
        FMIXHI(a3, (Q), o1); \
        t1 = dpp_wave_shr1(a3); \
    } while (0)

    // single raw barrier: LDS-visibility only (lgkmcnt), prefetch NOT drained
    #define BARR do { \
        asm volatile("s_waitcnt lgkmcnt(0)" ::: "memory"); \
        __builtin_amdgcn_s_barrier(); \
        asm volatile("" ::: "memory"); \
    } while (0)

    // every 16 steps: boundary handoff + block-max pow2 rescale. Wave w lanes
    // 56..63 (owned top 32 states = next wave's halo) -> LDS buffer [pp];
    // wave w>0 lanes 0..7 reload; all scale by 2^-e of block max. SINGLE
    // barrier: next exchange writes buffer [pp^1] (WAR distance = 16 steps).
    #define EXCHANGE(PP) do { \
        float mx = fmaxf(fmaxf(a0, a1), fmaxf(a2, a3)); \
        mx = fmaxf(mx, dpp_mov<0x111>(mx)); \
        mx = fmaxf(mx, dpp_mov<0x112>(mx)); \
        mx = fmaxf(mx, dpp_mov<0x114>(mx)); \
        mx = fmaxf(mx, dpp_mov<0x118>(mx)); \
        mx = fmaxf(mx, dpp_mov<0x142>(mx)); \
        mx = fmaxf(mx, dpp_mov<0x143>(mx)); \
        if (lane == 63) wmax_sh[PP][wid] = mx; \
        if (lane >= 56) { \
            float4 bv; bv.x = a0; bv.y = a1; bv.z = a2; bv.w = a3; \
            *reinterpret_cast<float4*>(&halo_sh[PP][wid][(lane - 56) * 4]) = bv; \
        } \
        BARR; \
        float bm = fmaxf(fmaxf(wmax_sh[PP][0], wmax_sh[PP][1]), \
                         fmaxf(wmax_sh[PP][2], wmax_sh[PP][3])); \
        int e = (int)((__float_as_uint(bm) >> 23) & 0xFF) - 127; \
        E += e; \
        const float sc = __uint_as_float((uint32_t)(127 - e) << 23);  /* 2^-e exact */ \
        if (wid > 0 && lane < 8) { \
            float4 hv = *reinterpret_cast<const float4*>(&halo_sh[PP][wid - 1][lane * 4]); \
            a0 = hv.x; a1 = hv.y; a2 = hv.z; a3 = hv.w; \
        } \
        a0 *= sc; a1 *= sc; a2 *= sc; a3 *= sc; \
        t1 = dpp_wave_shr1(a3); \
    } while (0)

    uint32_t q0,q1,q2,q3,q4,q5,q6,q7,q8,q9,q10,q11,q12,q13,q14,q15;
    LOADG4(q0,q1,q2,q3); LOADG4(q4,q5,q6,q7);
    LOADG4(q8,q9,q10,q11); LOADG4(q12,q13,q14,q15);

    int t = 1;
    int pp = 0;
    while (t + 15 < Tn) {
        STEPF(q0);  STEPF(q1);  STEPF(q2);  STEPF(q3);  LOADG4(q0,q1,q2,q3);
        STEPF(q4);  STEPF(q5);  STEPF(q6);  STEPF(q7);  LOADG4(q4,q5,q6,q7);
        STEPF(q8);  STEPF(q9);  STEPF(q10); STEPF(q11); LOADG4(q8,q9,q10,q11);
        STEPF(q12); STEPF(q13); STEPF(q14); STEPF(q15); LOADG4(q12,q13,q14,q15);
        EXCHANGE(pp);
        pp ^= 1;
        t += 16;
    }
    {
        const int r = Tn - t;   // 0..15; halo degradation <= 30 <= 32 -> owned ok
        if (r > 0)  STEPF(q0);
        if (r > 1)  STEPF(q1);
        if (r > 2)  STEPF(q2);
        if (r > 3)  STEPF(q3);
        if (r > 4)  STEPF(q4);
        if (r > 5)  STEPF(q5);
        if (r > 6)  STEPF(q6);
        if (r > 7)  STEPF(q7);
        if (r > 8)  STEPF(q8);
        if (r > 9)  STEPF(q9);
        if (r > 10) STEPF(q10);
        if (r > 11) STEPF(q11);
        if (r > 12) STEPF(q12);
        if (r > 13) STEPF(q13);
        if (r > 14) STEPF(q14);
    }

    // readout: owned lanes (>=8) publish their 4 states
    if (lane >= 8) {
        const int gidx = 224 * wid - 32 + 4 * lane;   // global state index of a0
        afin[gidx]     = a0;
        afin[gidx + 1] = a1;
        afin[gidx + 2] = a2;
        afin[gidx + 3] = a3;
    }
    __syncthreads();
    if (tid == 0) {
        float tot = afin[2 * L] + afin[2 * L - 1];
        float lossb = 0.0f;
        if (tot > 0.0f) {
            double ll = log((double)tot)
                      + (double)E * 0.69314718055994530942
                      + (double)(-(double)Tn - (double)sl);
            lossb = (float)(-ll / (double)L);
        }
        loss_out[b] = lossb;
    }
    #undef STEPF
    #undef FMIXLO
    #undef FMIXHI
    #undef LOADG4
    #undef BARR
    #undef EXCHANGE
}

// ------------------------------------------------- fallback (round-3, proven)
__global__ __launch_bounds__(256)
void lse_kernel(const float* __restrict__ ap_all,
                const int* __restrict__ in_lens,
                float* __restrict__ lse_out)
{
    const int lane = threadIdx.x & 63;
    const int wglob = blockIdx.x * (blockDim.x >> 6) + (threadIdx.x >> 6);
    const int nwav = gridDim.x * (blockDim.x >> 6);
    const int nrows = 64 * T_MAXN;

    for (int row = wglob; row < nrows; row += nwav) {
        const int b = row / T_MAXN;
        const int L = in_lens[b];
        const float* rp = ap_all + (size_t)row * K_MAXN;
        const int c0 = lane * 8;
        const int cb = (c0 < 392) ? c0 : 392;
        const float4* p = reinterpret_cast<const float4*>(rp + cb);
        float4 x0 = p[0], x1 = p[1];
        float v[8] = {x0.x, x0.y, x0.z, x0.w, x1.x, x1.y, x1.z, x1.w};
        float m = -1.0f;
        #pragma unroll
        for (int j = 0; j < 8; ++j) {
            v[j] = (c0 + j < L) ? v[j] : -1e30f;
            m = fmaxf(m, v[j]);
        }
        #pragma unroll
        for (int off = 32; off; off >>= 1) m = fmaxf(m, __shfl_xor(m, off));
        float s = (lane == 0) ? __expf(-1.0f - m) : 0.0f;
        #pragma unroll
        for (int j = 0; j < 8; ++j) s += __expf(v[j] - m);
        #pragma unroll
        for (int off = 32; off; off >>= 1) s += __shfl_xor(s, off);
        if (lane == 0) lse_out[row] = m + __logf(s);
    }
}

__global__ __launch_bounds__(64)
void ctc_scan_kernel(const float* __restrict__ ap_all,
                     const int* __restrict__ in_lens,
                     const int* __restrict__ out_lens,
                     const float* __restrict__ lse_all,
                     float* __restrict__ loss_out)
{
    __shared__ float afin[1024];

    const int b    = blockIdx.x;
    const int lane = threadIdx.x;
    const int L    = in_lens[b];
    const int Tn   = out_lens[b];
    const float* ap  = ap_all + (size_t)b * (T_MAXN * K_MAXN);
    const float* lse = lse_all + b * T_MAXN;

    const float LOG2E = 1.4426950408889634f;
    const int c0 = lane * 8;
    const int cb = (c0 < 392) ? c0 : 392;
    const float* rbase = ap + cb;
    float fa0,fa1,fa2,fa3,fa4,fa5,fa6,fa7;
    float fb0,fb1,fb2,fb3,fb4,fb5,fb6,fb7;
    #define MASKC(J, FA, FB) do { bool ok = (c0 + (J)) < L; \
        FA = ok ? LOG2E : 0.0f; FB = ok ? LOG2E : -1000.0f; } while (0)
    MASKC(0,fa0,fb0); MASKC(1,fa1,fb1); MASKC(2,fa2,fb2); MASKC(3,fa3,fb3);
    MASKC(4,fa4,fb4); MASKC(5,fa5,fb5); MASKC(6,fa6,fb6); MASKC(7,fa7,fb7);
    #undef MASKC

    float4 p0a,p0b,p1a,p1b,p2a,p2b,p3a,p3b;
    #define LOADROW(PA, PB, T) do { \
        const float4* _p = reinterpret_cast<const float4*>(rbase + (size_t)(T) * K_MAXN); \
        PA = _p[0]; PB = _p[1]; } while (0)
    LOADROW(p0a,p0b,1); LOADROW(p1a,p1b,2); LOADROW(p2a,p2b,3); LOADROW(p3a,p3b,4);

    float sl = 0.0f;
    for (int t = lane; t < Tn; t += 64) sl += lse[t];
    #pragma unroll
    for (int off = 32; off; off >>= 1) sl += __shfl_xor(sl, off);

    float x00 = ap[0];
    float a0=0,a1=0,a2=0,a3=0,a4=0,a5=0,a6=0,a7=0;
    float a8=0,a9=0,a10=0,a11=0,a12=0,a13=0,a14=0,a15=0;
    if (lane == 0) {
        a0 = 1.0f;
        a1 = __builtin_amdgcn_exp2f(fmaf(x00, LOG2E, LOG2E));
    }
    int E = 0;

    #define STEP(A0, A1) do { \
        float t1 = __shfl_up(a15, 1); \
        t1 = lane ? t1 : 0.0f; \
        const float f0 = __builtin_amdgcn_exp2f(fmaf((A0).x, fa0, fb0)); \
        const float f1 = __builtin_amdgcn_exp2f(fmaf((A0).y, fa1, fb1)); \
        const float f2 = __builtin_amdgcn_exp2f(fmaf((A0).z, fa2, fb2)); \
        const float f3 = __builtin_amdgcn_exp2f(fmaf((A0).w, fa3, fb3)); \
        const float f4 = __builtin_amdgcn_exp2f(fmaf((A1).x, fa4, fb4)); \
        const float f5 = __builtin_amdgcn_exp2f(fmaf((A1).y, fa5, fb5)); \
        const float f6 = __builtin_amdgcn_exp2f(fmaf((A1).z, fa6, fb6)); \
        const float f7 = __builtin_amdgcn_exp2f(fmaf((A1).w, fa7, fb7)); \
        const float e0 = a0 + t1,   e1 = a2 + a1,   e2 = a4 + a3,   e3 = a6 + a5; \
        const float e4 = a8 + a7,   e5 = a10 + a9,  e6 = a12 + a11, e7 = a14 + a13; \
        const float o0 = a1 + e0,   o1 = a3 + e1,   o2 = a5 + e2,   o3 = a7 + e3; \
        const float o4 = a9 + e4,   o5 = a11 + e5,  o6 = a13 + e6,  o7 = a15 + e7; \
        a0 = e0; a2 = e1; a4 = e2; a6 = e3; a8 = e4; a10 = e5; a12 = e6; a14 = e7; \
        a1 = f0*o0; a3 = f1*o1; a5 = f2*o2; a7 = f3*o3; \
        a9 = f4*o4; a11 = f5*o5; a13 = f6*o6; a15 = f7*o7; \
    } while (0)

    #define RESCALE do { \
        float mx = fmaxf(fmaxf(fmaxf(fmaxf(a0,a1),fmaxf(a2,a3)),fmaxf(fmaxf(a4,a5),fmaxf(a6,a7))), \
                         fmaxf(fmaxf(fmaxf(a8,a9),fmaxf(a10,a11)),fmaxf(fmaxf(a12,a13),fmaxf(a14,a15)))); \
        _Pragma("unroll") \
        for (int off = 32; off; off >>= 1) mx = fmaxf(mx, __shfl_xor(mx, off)); \
        int e = (int)((__float_as_uint(mx) >> 23) & 0xFF) - 127; \
        if (e != 0) { \
            E += e; \
            a0 = ldexpf(a0,-e);  a1 = ldexpf(a1,-e);  a2 = ldexpf(a2,-e);  a3 = ldexpf(a3,-e); \
            a4 = ldexpf(a4,-e);  a5 = ldexpf(a5,-e);  a6 = ldexpf(a6,-e);  a7 = ldexpf(a7,-e); \
            a8 = ldexpf(a8,-e);  a9 = ldexpf(a9,-e);  a10= ldexpf(a10,-e); a11= ldexpf(a11,-e); \
            a12= ldexpf(a12,-e); a13= ldexpf(a13,-e); a14= ldexpf(a14,-e); a15= ldexpf(a15,-e); \
        } \
    } while (0)

    int t = 1;
    while (t + 3 < Tn) {
        int tl;
        STEP(p0a,p0b); tl = (t+4 < T_MAXN) ? t+4 : T_MAXN-1; LOADROW(p0a,p0b,tl);
        STEP(p1a,p1b); tl = (t+5 < T_MAXN) ? t+5 : T_MAXN-1; LOADROW(p1a,p1b,tl);
        STEP(p2a,p2b); tl = (t+6 < T_MAXN) ? t+6 : T_MAXN-1; LOADROW(p2a,p2b,tl);
        STEP(p3a,p3b); tl = (t+7 < T_MAXN) ? t+7 : T_MAXN-1; LOADROW(p3a,p3b,tl);
        if ((t & 7) == 5) RESCALE;
        t += 4;
    }
    if (t < Tn) { STEP(p0a,p0b); ++t; }
    if (t < Tn) { STEP(p1a,p1b); ++t; }
    if (t < Tn) { STEP(p2a,p2b); ++t; }

    afin[16*lane+0]=a0;  afin[16*lane+1]=a1;  afin[16*lane+2]=a2;  afin[16*lane+3]=a3;
    afin[16*lane+4]=a4;  afin[16*lane+5]=a5;  afin[16*lane+6]=a6;  afin[16*lane+7]=a7;
    afin[16*lane+8]=a8;  afin[16*lane+9]=a9;  afin[16*lane+10]=a10; afin[16*lane+11]=a11;
    afin[16*lane+12]=a12; afin[16*lane+13]=a13; afin[16*lane+14]=a14; afin[16*lane+15]=a15;
    __syncthreads();
    if (lane == 0) {
        float tot = afin[2*L] + afin[2*L-1];
        float lossb = 0.0f;
        if (tot > 0.0f) {
            double ll = log((double)tot)
                      + (double)E * 0.69314718055994530942
                      + (double)(-(double)Tn - (double)sl);
            lossb = (float)(-ll / (double)L);
        }
        loss_out[b] = lossb;
    }
    #undef STEP
    #undef RESCALE
    #undef LOADROW
}

// ---------------------------------------------------------------- mean
__global__ void mean_kernel(const float* __restrict__ loss, float* __restrict__ out)
{
    float v = loss[threadIdx.x];   // 64 threads
    #pragma unroll
    for (int off = 32; off; off >>= 1) v += __shfl_xor(v, off);
    if (threadIdx.x == 0) out[0] = v * (1.0f / 64.0f);
}

extern "C" void kernel_launch(void* const* d_in, const int* in_sizes, int n_in,
                              void* d_out, int out_size, void* d_ws, size_t ws_size,
                              hipStream_t stream)
{
    // setup_inputs order: attn (unused), in_lens, out_lens, attn_logprob
    const int*   in_lens  = (const int*)d_in[1];
    const int*   out_lens = (const int*)d_in[2];
    const float* ap       = (const float*)d_in[3];
    float*       out      = (float*)d_out;

    if (ws_size >= WS_NEED) {
        char*     wsb     = (char*)d_ws;
        _Float16* g       = (_Float16*)wsb;
        float*    lse_ws  = (float*)(wsb + LSE_OFF);
        float*    zb      = (float*)(wsb + ZERO_OFF);
        float*    loss_ws = (float*)(wsb + LOSS_OFF);
        hipLaunchKernelGGL(prep_kernel, dim3(32, 64), dim3(256), 0, stream,
                           ap, in_lens, out_lens, lse_ws, g, zb);
        hipLaunchKernelGGL(ctc_scan4w_kernel, dim3(64), dim3(256), 0, stream,
                           (const char*)wsb, in_lens, out_lens, loss_ws);
        hipLaunchKernelGGL(mean_kernel, dim3(1), dim3(64), 0, stream, loss_ws, out);
    } else {
        float* lse_ws  = (float*)d_ws;
        float* loss_ws = (float*)((char*)d_ws + (size_t)64 * T_MAXN * 4);
        hipLaunchKernelGGL(lse_kernel, dim3(512), dim3(256), 0, stream,
                           ap, in_lens, lse_ws);
        hipLaunchKernelGGL(ctc_scan_kernel, dim3(64), dim3(64), 0, stream,
                           ap, in_lens, out_lens, lse_ws, loss_ws);
        hipLaunchKernelGGL(mean_kernel, dim3(1), dim3(64), 0, stream, loss_ws, out);
    }
}